// Round 9
// baseline (164.476 us; speedup 1.0000x reference)
//
#include <hip/hip_runtime.h>
#include <math.h>

// B=2, Lq=1024, C=256, H=W=64 -> Lk=4096, NC=2, NH=8, D=32.
// R18: k3 weight-load depth attack. Each GEMM part prefetches BOTH jj's
// weight rows into wfr2[2][8] (16 loads in flight, 64 VGPR) before any
// MFMA -> exposed L3/HBM latency rounds per part 6 -> 3. K stored right
// after K part (short kacc live range; stores overlap V-part loads).
// k56 gets the same paired-j weight prefetch. attn/k1 unchanged from R17.

#define LQ 1024
#define HW 4096
#define LOG2E 1.4426950408889634f

typedef __attribute__((ext_vector_type(8))) short short8;
typedef __attribute__((ext_vector_type(4))) float f32x4;
typedef unsigned short u16;

__device__ __forceinline__ u16 bf16r(float x) {
    unsigned int u = __float_as_uint(x);
    u = (u + 0x7FFFu + ((u >> 16) & 1u)) >> 16;
    return (u16)u;
}

__device__ __forceinline__ float b2f(u16 v) {
    return __uint_as_float((unsigned)v << 16);
}

__device__ __forceinline__ float ent2(float a, float b) {
    float m  = fmaxf(a, b);
    float e0 = expf(a - m), e1 = expf(b - m);
    float iz = 1.f / (e0 + e1);
    float p0 = fmaxf(e0 * iz, 1e-8f);
    float p1 = fmaxf(e1 * iz, 1e-8f);
    return -(p0 * logf(p0) + p1 * logf(p1));
}

typedef __attribute__((address_space(1))) const unsigned int gas_u32;
typedef __attribute__((address_space(3))) unsigned int las_u32;
__device__ __forceinline__ void glds16(const void* g, void* l) {
    __builtin_amdgcn_global_load_lds((gas_u32*)g, (las_u32*)l, 16, 0, 0);
}

// kv-permutation within a 32-group: p(16t + 4q2 + r) = 8*q2 + 4*t + r
__device__ __forceinline__ int kvperm(int l) {
    int w = l & 31;
    return (l & ~31) | (((w >> 2) & 3) << 3) | (((w >> 4) & 1) << 2) | (w & 3);
}

// ---- fused-weight GEMM, all-inline from fp32:
// out16[a*256+b] = sum_o G[o*256+a] * S[b*256+o]
__device__ __forceinline__ void fuse_gemm(int bid, const float* __restrict__ G,
                                          const float* __restrict__ S,
                                          u16* __restrict__ out16) {
    const int wv = threadIdx.x >> 6, lane = threadIdx.x & 63;
    const int lm = lane & 15, quad = lane >> 4;
    const int row0 = (bid >> 1) * 32;          // a
    const int c0 = (bid & 1) * 128 + wv * 32;  // b
    short8 af[2][8];
#pragma unroll
    for (int s = 0; s < 2; ++s)
#pragma unroll
        for (int i = 0; i < 8; ++i) {
            short8 t;
#pragma unroll
            for (int j = 0; j < 8; ++j)
                t[j] = (short)bf16r(G[(size_t)(i * 32 + quad * 8 + j) * 256 +
                                      row0 + s * 16 + lm]);
            af[s][i] = t;
        }
#pragma unroll
    for (int j = 0; j < 2; ++j) {
        int b = c0 + j * 16 + lm;
        f32x4 acc[2];
        acc[0] = f32x4{0.f, 0.f, 0.f, 0.f};
        acc[1] = acc[0];
#pragma unroll
        for (int i = 0; i < 8; ++i) {
            const float* sp = S + (size_t)b * 256 + i * 32 + quad * 8;
            float4 f0 = *(const float4*)sp;
            float4 f1 = *(const float4*)(sp + 4);
            short8 bfv;
            bfv[0] = (short)bf16r(f0.x); bfv[1] = (short)bf16r(f0.y);
            bfv[2] = (short)bf16r(f0.z); bfv[3] = (short)bf16r(f0.w);
            bfv[4] = (short)bf16r(f1.x); bfv[5] = (short)bf16r(f1.y);
            bfv[6] = (short)bf16r(f1.z); bfv[7] = (short)bf16r(f1.w);
#pragma unroll
            for (int s = 0; s < 2; ++s)
                acc[s] = __builtin_amdgcn_mfma_f32_16x16x32_bf16(af[s][i], bfv,
                                                                 acc[s], 0, 0, 0);
        }
#pragma unroll
        for (int s = 0; s < 2; ++s)
#pragma unroll
            for (int r = 0; r < 4; ++r)
                out16[(size_t)(row0 + s * 16 + quad * 4 + r) * 256 + b] =
                    bf16r(acc[s][r]);
    }
}

// ======== K1: prep (386 blocks)
__global__ __launch_bounds__(256) void k1_prep(
    const float* qpW1hi, const float* Wk, const float* Wv, const float* phiQ1,
    const float* Wq, const float* phiW, const float* phiQ2, const float* Wo,
    u16* qpW1loT, u16* WkT, u16* WvT, u16* phiQ1T, u16* Wf1T, u16* Wf2T,
    const float* pb2, const float* bq, const float* bo, const float* phib,
    float* bf1, float* bf2,
    const float* S_SM, const float* qpW1full, float* sbp) {
    __shared__ float tile[32][33];
    __shared__ float part_s[256];
    __shared__ float4 red4[4][64];
    int bid = blockIdx.x;
    if (bid < 320) {  // transposes W[K,256] -> Wt[256,K] bf16
        const float* S; u16* D; int K;
        if (bid < 64)       { S = qpW1hi; D = qpW1loT; K = 256; }
        else if (bid < 128) { S = Wk; D = WkT; K = 256; bid -= 64; }
        else if (bid < 192) { S = Wv; D = WvT; K = 256; bid -= 128; }
        else                { S = phiQ1; D = phiQ1T; K = 512; bid -= 192; }
        int KT = K >> 5;
        int tk = bid % KT, tn = bid / KT;
        int cc = threadIdx.x & 31, rb = threadIdx.x >> 5;
#pragma unroll
        for (int i = 0; i < 4; ++i) {
            int rr = rb + i * 8;
            tile[rr][cc] = S[(size_t)(tk * 32 + rr) * 256 + tn * 32 + cc];
        }
        __syncthreads();
#pragma unroll
        for (int i = 0; i < 4; ++i) {
            int rr = rb + i * 8;
            D[(size_t)(tn * 32 + rr) * K + tk * 32 + cc] = bf16r(tile[cc][rr]);
        }
    } else if (bid < 336) {  // Wf1T[n][c] = sum_o phiQ2[c][o] * Wq[o][n]
        fuse_gemm(bid - 320, Wq, phiQ2, Wf1T);
    } else if (bid < 352) {  // Wf2T[n][d] = sum_o Wo[d][o] * phiW[o][n]
        fuse_gemm(bid - 336, phiW, Wo, Wf2T);
    } else if (bid < 354) {  // bias_fuse
        int n = threadIdx.x;
        if (bid == 352) {
            float a = bq[n];
#pragma unroll 8
            for (int c = 0; c < 256; ++c) a += pb2[c] * Wq[c * 256 + n];
            bf1[n] = a;
        } else {
            float a = phib[n];
#pragma unroll 8
            for (int c = 0; c < 256; ++c) a += bo[c] * phiW[c * 256 + n];
            bf2[n] = a;
        }
    } else {  // mean partial + partial sbias matvec: 32 slabs of 64 rows
        int bi = bid - 354;
        int bb = bi >> 4, l0 = (bi & 15) * 64;
        int c = threadIdx.x;
        const float* p = S_SM + (size_t)bb * LQ * 256 + (size_t)l0 * 256 + c;
        float acc = 0.f;
#pragma unroll 8
        for (int l = 0; l < 64; ++l) acc += p[(size_t)l * 256];
        part_s[c] = acc;
        __syncthreads();
        const int g = threadIdx.x & 63, qtr = threadIdx.x >> 6;
        float a0 = 0.f, a1 = 0.f, a2 = 0.f, a3 = 0.f;
        const float* wbase = qpW1full + (size_t)(qtr * 64) * 256 + g * 4;
#pragma unroll 8
        for (int i = 0; i < 64; ++i) {
            float pp = part_s[qtr * 64 + i];
            float4 w = *(const float4*)(wbase + (size_t)i * 256);
            a0 += pp * w.x; a1 += pp * w.y; a2 += pp * w.z; a3 += pp * w.w;
        }
        red4[qtr][g] = float4{a0, a1, a2, a3};
        __syncthreads();
        if (threadIdx.x < 64) {
            int t = threadIdx.x;
            float4 r0 = red4[0][t], r1 = red4[1][t], r2 = red4[2][t], r3 = red4[3][t];
            float4 s;
            s.x = r0.x + r1.x + r2.x + r3.x;
            s.y = r0.y + r1.y + r2.y + r3.y;
            s.z = r0.z + r1.z + r2.z + r3.z;
            s.w = r0.w + r1.w + r2.w + r3.w;
            *(float4*)(sbp + (size_t)bi * 256 + t * 4) = s;
        }
    }
}

// ======== K3: proj (384 blocks x 512 threads)
__global__ __launch_bounds__(512, 2) void k3_proj(
    const float* __restrict__ f_q, const u16* __restrict__ Wqp,
    const u16* __restrict__ Wk, const u16* __restrict__ Wv,
    const float* __restrict__ sbp, const float* __restrict__ qpb1,
    const float* __restrict__ qpW2, const float* __restrict__ qpb2,
    const float* __restrict__ P, const float* __restrict__ bk,
    const float* __restrict__ bv,
    float* __restrict__ outPhat, float* __restrict__ outV,
    u16* __restrict__ evb, u16* __restrict__ kmb, u16* __restrict__ vtb,
    const float* __restrict__ S_QP, const float* __restrict__ S_SM,
    const u16* __restrict__ phiQ1T, const float* __restrict__ phiQb1,
    const u16* __restrict__ Wf1T, const float* __restrict__ bf1,
    float qscale, u16* __restrict__ qmb) {
    __shared__ __align__(16) u16 shmem[32 * 264];
    __shared__ float sb_s[256];
    __shared__ float red[8][32][2];
    __shared__ float evl[32];
    const int bid = blockIdx.x;
    const int tid = threadIdx.x;
    const int wv = tid >> 6, lane = tid & 63;
    const int lm = lane & 15, quad = lane >> 4;
    if (bid >= 256) {  // ---- phiQ1 + q-proj fused: 16 rows per block
        __shared__ __align__(16) u16 fs2[16 * 520];
        u16* qs = shmem;  // [16][264] Qmid
        const int row0 = (bid - 256) * 16;
        {   // stage (coalesced): 16-lane halves read 1KB contiguous rows
            int r = tid >> 5, cg = tid & 31;
            const float* src = (cg < 16)
                ? (S_QP + (size_t)(row0 + r) * 256 + cg * 16)
                : (S_SM + (size_t)(row0 + r) * 256 + (cg - 16) * 16);
            u16* dst = fs2 + r * 520 + cg * 16;
#pragma unroll
            for (int q4 = 0; q4 < 4; ++q4) {
                float4 f0 = *(const float4*)(src + q4 * 4);
                dst[q4 * 4 + 0] = bf16r(f0.x);
                dst[q4 * 4 + 1] = bf16r(f0.y);
                dst[q4 * 4 + 2] = bf16r(f0.z);
                dst[q4 * 4 + 3] = bf16r(f0.w);
            }
        }
        __syncthreads();
        short8 af[16];
#pragma unroll
        for (int i = 0; i < 16; ++i)
            af[i] = *(const short8*)(fs2 + lm * 520 + i * 32 + quad * 8);
#pragma unroll
        for (int j = 0; j < 2; ++j) {
            int n = wv * 32 + j * 16 + lm;
            short8 wfr[16];
            const u16* wp = phiQ1T + (size_t)n * 512 + quad * 8;
#pragma unroll
            for (int i = 0; i < 16; ++i) wfr[i] = *(const short8*)(wp + i * 32);
            float bvv = phiQb1[n];
            f32x4 acc = {bvv, bvv, bvv, bvv};
#pragma unroll
            for (int i = 0; i < 16; ++i)
                acc = __builtin_amdgcn_mfma_f32_16x16x32_bf16(af[i], wfr[i], acc, 0, 0, 0);
#pragma unroll
            for (int r = 0; r < 4; ++r)
                qs[(quad * 4 + r) * 264 + n] = bf16r(fmaxf(acc[r], 0.f));
        }
        __syncthreads();
        short8 aq[8];
#pragma unroll
        for (int i = 0; i < 8; ++i)
            aq[i] = *(const short8*)(qs + lm * 264 + i * 32 + quad * 8);
#pragma unroll
        for (int j = 0; j < 2; ++j) {
            int n = wv * 32 + j * 16 + lm;
            short8 wfr[8];
            const u16* wp = Wf1T + (size_t)n * 256 + quad * 8;
#pragma unroll
            for (int i = 0; i < 8; ++i) wfr[i] = *(const short8*)(wp + i * 32);
            float bvv = bf1[n];
            f32x4 acc = {bvv, bvv, bvv, bvv};
#pragma unroll
            for (int i = 0; i < 8; ++i)
                acc = __builtin_amdgcn_mfma_f32_16x16x32_bf16(aq[i], wfr[i], acc, 0, 0, 0);
#pragma unroll
            for (int r = 0; r < 4; ++r)
                qmb[(size_t)(row0 + quad * 4 + r) * 256 + n] = bf16r(acc[r] * qscale);
        }
        return;
    }
    // ---- fused qp + K + V, BM=32
    u16* fs = shmem;  // [32][264] staged f_q tile (bf16), [pos][ch]
    const int row0 = bid * 32;
    const int b = row0 >> 12;
    const int l = row0 & 4095;
    {   // stage (coalesced): 8-lane groups read 128B contiguous per ch row
        int cg = tid >> 3;        // 0..63
        int l4 = (tid & 7) * 4;   // 0,4,...,28
        const float* fb0 = f_q + (size_t)b * 256 * HW + l;
#pragma unroll
        for (int g = 0; g < 4; ++g) {
            int c = g * 64 + cg;
            float4 v = *(const float4*)(fb0 + (size_t)c * HW + l4);
            u16* dst = fs + c;
            dst[(l4 + 0) * 264] = bf16r(v.x);
            dst[(l4 + 1) * 264] = bf16r(v.y);
            dst[(l4 + 2) * 264] = bf16r(v.z);
            dst[(l4 + 3) * 264] = bf16r(v.w);
        }
    }
    if (tid < 256) {  // sbias: sum 16 precomputed partial matvecs
        float a = 0.f;
#pragma unroll
        for (int p = 0; p < 16; ++p) a += sbp[(b * 16 + p) * 256 + tid];
        sb_s[tid] = qpb1[tid] + a * (1.f / 1024.f);
    }
    __syncthreads();
    short8 af[2][8];  // register-resident A frags
#pragma unroll
    for (int rg = 0; rg < 2; ++rg)
#pragma unroll
        for (int i = 0; i < 8; ++i)
            af[rg][i] = *(const short8*)(fs + (rg * 16 + lm) * 264 + i * 32 + quad * 8);
    const int n0 = wv * 32 + lm;   // jj=0 row; jj=1 row is n0+16
    // --- qp part (paired-jj prefetch: 16 loads in flight)
    float c0p[2][4] = {{0.f, 0.f, 0.f, 0.f}, {0.f, 0.f, 0.f, 0.f}};
    float c1p[2][4] = {{0.f, 0.f, 0.f, 0.f}, {0.f, 0.f, 0.f, 0.f}};
    {
        short8 wfr2[2][8];
#pragma unroll
        for (int jj = 0; jj < 2; ++jj) {
            const u16* wp = Wqp + (size_t)(n0 + jj * 16) * 256 + quad * 8;
#pragma unroll
            for (int i = 0; i < 8; ++i) wfr2[jj][i] = *(const short8*)(wp + i * 32);
        }
#pragma unroll
        for (int jj = 0; jj < 2; ++jj) {
            const int n = n0 + jj * 16;
            float bv2 = sb_s[n];
            float w20 = qpW2[n * 2], w21 = qpW2[n * 2 + 1];
#pragma unroll
            for (int rg = 0; rg < 2; ++rg) {
                f32x4 acc = {bv2, bv2, bv2, bv2};
#pragma unroll
                for (int i = 0; i < 8; ++i)
                    acc = __builtin_amdgcn_mfma_f32_16x16x32_bf16(af[rg][i], wfr2[jj][i], acc, 0, 0, 0);
#pragma unroll
                for (int r = 0; r < 4; ++r) {
                    float hh2 = fmaxf(acc[r], 0.f);
                    c0p[rg][r] += hh2 * w20;
                    c1p[rg][r] += hh2 * w21;
                }
            }
        }
    }
    // --- K part (paired-jj prefetch) + immediate store
    {
        short8 wfr2[2][8];
#pragma unroll
        for (int jj = 0; jj < 2; ++jj) {
            const u16* wp = Wk + (size_t)(n0 + jj * 16) * 256 + quad * 8;
#pragma unroll
            for (int i = 0; i < 8; ++i) wfr2[jj][i] = *(const short8*)(wp + i * 32);
        }
#pragma unroll
        for (int jj = 0; jj < 2; ++jj) {
            const int n = n0 + jj * 16;
            float bk2 = bk[n];
#pragma unroll
            for (int rg = 0; rg < 2; ++rg) {
                f32x4 acc = {bk2, bk2, bk2, bk2};
#pragma unroll
                for (int i = 0; i < 8; ++i)
                    acc = __builtin_amdgcn_mfma_f32_16x16x32_bf16(af[rg][i], wfr2[jj][i], acc, 0, 0, 0);
#pragma unroll
                for (int r = 0; r < 4; ++r)
                    kmb[(size_t)(row0 + rg * 16 + quad * 4 + r) * 256 + n] =
                        bf16r(acc[r]);
            }
        }
    }
    // --- V part (paired-jj prefetch), accs held across barriers
    f32x4 vacc[2][2];
    {
        short8 wfr2[2][8];
#pragma unroll
        for (int jj = 0; jj < 2; ++jj) {
            const u16* wp = Wv + (size_t)(n0 + jj * 16) * 256 + quad * 8;
#pragma unroll
            for (int i = 0; i < 8; ++i) wfr2[jj][i] = *(const short8*)(wp + i * 32);
        }
#pragma unroll
        for (int jj = 0; jj < 2; ++jj) {
            float bv2 = bv[n0 + jj * 16];
#pragma unroll
            for (int rg = 0; rg < 2; ++rg) {
                f32x4 acc = {bv2, bv2, bv2, bv2};
#pragma unroll
                for (int i = 0; i < 8; ++i)
                    acc = __builtin_amdgcn_mfma_f32_16x16x32_bf16(af[rg][i], wfr2[jj][i], acc, 0, 0, 0);
                vacc[jj][rg] = acc;
            }
        }
    }
    // qp wave reduce
#pragma unroll
    for (int m = 1; m < 16; m <<= 1) {
#pragma unroll
        for (int rg = 0; rg < 2; ++rg)
#pragma unroll
            for (int r = 0; r < 4; ++r) {
                c0p[rg][r] += __shfl_xor(c0p[rg][r], m);
                c1p[rg][r] += __shfl_xor(c1p[rg][r], m);
            }
    }
    if (lm == 0) {
#pragma unroll
        for (int rg = 0; rg < 2; ++rg)
#pragma unroll
            for (int r = 0; r < 4; ++r) {
                red[wv][rg * 16 + quad * 4 + r][0] = c0p[rg][r];
                red[wv][rg * 16 + quad * 4 + r][1] = c1p[rg][r];
            }
    }
    __syncthreads();
    if (tid < 32) {
        int t = tid;
        float ph0 = qpb2[0], ph1 = qpb2[1];
#pragma unroll
        for (int w = 0; w < 8; ++w) {
            ph0 += red[w][t][0];
            ph1 += red[w][t][1];
        }
        int hw = l + t;
        float Vv = ent2(ph0, ph1) -
                   ent2(P[(size_t)b * 8192 + hw], P[(size_t)b * 8192 + 4096 + hw]);
        outPhat[(size_t)b * 8192 + hw] = ph0;
        outPhat[(size_t)b * 8192 + 4096 + hw] = ph1;
        outV[b * 4096 + hw] = Vv;
        float ev = expf(Vv);
        evl[t] = ev;
        evb[b * HW + kvperm(hw)] = bf16r(ev);
    }
    __syncthreads();  // evl visible to all
    // V scale + store (kvperm, r-packed)
#pragma unroll
    for (int jj = 0; jj < 2; ++jj) {
        const int n = n0 + jj * 16;
#pragma unroll
        for (int rg = 0; rg < 2; ++rg) {
            const int pbase = l | (quad << 3) | (rg << 2);
            ushort4 pk;
            pk.x = bf16r(vacc[jj][rg][0] * evl[rg * 16 + quad * 4 + 0]);
            pk.y = bf16r(vacc[jj][rg][1] * evl[rg * 16 + quad * 4 + 1]);
            pk.z = bf16r(vacc[jj][rg][2] * evl[rg * 16 + quad * 4 + 2]);
            pk.w = bf16r(vacc[jj][rg][3] * evl[rg * 16 + quad * 4 + 3]);
            *(ushort4*)(vtb + ((size_t)((b * 8 + (n >> 5)) * 32 + (n & 31))) * HW +
                        pbase) = pk;
        }
    }
}

// ======== K4: MFMA flash attention (sp x4, K_STEP=128, counted-vmcnt barrier)
__global__ __launch_bounds__(256) void attn_mfma(const u16* __restrict__ qm,
                                                 const u16* __restrict__ km,
                                                 const u16* __restrict__ vt,
                                                 const u16* __restrict__ evb,
                                                 u16* __restrict__ Op,
                                                 float* __restrict__ Lp) {
    // half-major: Kst[buf][half][kv 64][d 32], Vst[buf][half][d 32][kv' 64]
    __shared__ __align__(16) u16 Kst[3][4096];
    __shared__ __align__(16) u16 Vst[3][4096];
    __shared__ __align__(16) u16 est[1024];   // evb tile (kv_lo..kv_lo+1024)
    const int blk = blockIdx.x;   // 512 = 2b * 8qt * 4sp * 8h
    const int h = blk & 7, sp = (blk >> 3) & 3, qt = (blk >> 5) & 7, b = blk >> 8;
    const int tid = threadIdx.x;
    const int wv = tid >> 6, lane = tid & 63;
    const int lm = lane & 15, quad = lane >> 4;
    const int q0 = qt * 128 + wv * 32;
    short8 qf[2];
#pragma unroll
    for (int s = 0; s < 2; ++s)
        qf[s] = *(const short8*)(qm + ((size_t)(b * LQ + q0 + s * 16 + lm)) * 256 +
                                 h * 32 + quad * 8);
    const u16* kbh = km + (size_t)b * HW * 256 + h * 32;
    const u16* vbh = vt + (size_t)(b * 8 + h) * 32 * HW;
    const u16* eb = evb + (size_t)b * HW;
    const int krow = tid >> 2, kseg = tid & 3;
    const int vd = tid >> 3, vp = tid & 7, vs = (vp - vd) & 7;
    const int kv_lo = sp * 1024;
    const f32x4 z4 = {0.f, 0.f, 0.f, 0.f};
    f32x4 o[2][2] = {{z4, z4}, {z4, z4}};  // [qfrag][dtile], O^T C-layout
    f32x4 lr[2] = {z4, z4};
    const int vss = (quad + lm) & 7;
#define LOADT(ib, kvoff)                                                          \
    {                                                                             \
        glds16(kbh + (size_t)((kvoff) + krow) * 256 + kseg * 8,                   \
               &Kst[ib][wv * 512]);                                               \
        glds16(kbh + (size_t)((kvoff) + 64 + krow) * 256 + kseg * 8,              \
               &Kst[ib][2048 + wv * 512]);                                        \
        glds16(vbh + (size_t)vd * HW + (kvoff) + vs * 8, &Vst[ib][wv * 512]);     \
        glds16(vbh + (size_t)vd * HW + (kvoff) + 64 + vs * 8,                     \
               &Vst[ib][2048 + wv * 512]);                                        \
    }
    // evb tile -> LDS (waves 0/1; ef reads then cost lgkmcnt only, not vmcnt)
    if (wv == 0)      glds16(eb + kv_lo + lane * 8, &est[0]);
    else if (wv == 1) glds16(eb + kv_lo + 512 + lane * 8, &est[512]);
    LOADT(0, kv_lo);
    LOADT(1, kv_lo + 128);
    for (int c = 0; c < 8; ++c) {
        // counted drain: tile c (oldest 4 glds16) done; tile c+1's 4 stay live
        if (c < 7) asm volatile("s_waitcnt vmcnt(4)" ::: "memory");
        else       asm volatile("s_waitcnt vmcnt(0)" ::: "memory");
        __builtin_amdgcn_s_barrier();
        __builtin_amdgcn_sched_barrier(0);
        if (c + 2 < 8) LOADT((c + 2) % 3, kv_lo + (c + 2) * 128);
        const int idx = c % 3;
#pragma unroll
        for (int half = 0; half < 2; ++half) {
            const int ekc = c * 128 + half * 64;
            const u16* kbuf = &Kst[idx][half * 2048];
            const u16* vbuf = &Vst[idx][half * 2048];
            f32x4 st[2][4];
#pragma unroll
            for (int tt = 0; tt < 4; ++tt) {
                short8 kf = *(const short8*)(kbuf + (tt * 16 + lm) * 32 + quad * 8);
                st[0][tt] = __builtin_amdgcn_mfma_f32_16x16x32_bf16(kf, qf[0], z4, 0, 0, 0);
                st[1][tt] = __builtin_amdgcn_mfma_f32_16x16x32_bf16(kf, qf[1], z4, 0, 0, 0);
            }
            short8 pf[2][2];
#pragma unroll
            for (int s = 0; s < 2; ++s)
#pragma unroll
                for (int c2 = 0; c2 < 2; ++c2) {
                    short8 pk;
#pragma unroll
                    for (int j = 0; j < 8; ++j) {
                        float pv = __builtin_amdgcn_exp2f(st[s][c2 * 2 + (j >> 2)][j & 3]);
                        pk[j] = (short)(__float_as_uint(pv) >> 16);
                    }
                    pf[s][c2] = pk;
                }
#pragma unroll
            for (int c2 = 0; c2 < 2; ++c2) {
                short8 ef = *(const short8*)(est + ekc + c2 * 32 + quad * 8);
                short8 vf0 = *(const short8*)(vbuf + lm * 64 + ((c2 * 4 + vss) & 7) * 8);
                short8 vf1 = *(const short8*)(vbuf + (16 + lm) * 64 + ((c2 * 4 + vss) & 7) * 8);
#pragma unroll
                for (int s = 0; s < 2; ++s) {
                    lr[s] = __builtin_amdgcn_mfma_f32_16x16x32_bf16(ef, pf[s][c2], lr[s], 0, 0, 0);
                    o[s][0] = __builtin_amdgcn_mfma_f32_16x16x32_bf16(vf0, pf[s][c2], o[s][0], 0, 0, 0);
                    o[s][1] = __builtin_amdgcn_mfma_f32_16x16x32_bf16(vf1, pf[s][c2], o[s][1], 0, 0, 0);
                }
            }
        }
    }
#undef LOADT
#pragma unroll
    for (int s = 0; s < 2; ++s) {
        int qg = q0 + s * 16 + lm;
        size_t rbase = (size_t)sp * 16384 + (size_t)(b * 8 + h) * LQ + qg;
#pragma unroll
        for (int dt = 0; dt < 2; ++dt) {
            ushort4 pk = {bf16r(o[s][dt][0]), bf16r(o[s][dt][1]),
                          bf16r(o[s][dt][2]), bf16r(o[s][dt][3])};
            *(ushort4*)(Op + rbase * 32 + dt * 16 + quad * 4) = pk;
        }
        if (quad == 0) Lp[rbase] = lr[s][0];
    }
}

// ======== K56: combine (4 sp partials) + final GEMM, col-split x2 (256 blocks).
__global__ __launch_bounds__(256) void k56_out(const u16* __restrict__ Op,
                                               const float* __restrict__ Lp,
                                               const u16* __restrict__ Wf2T,
                                               const float* __restrict__ bf2,
                                               const float* __restrict__ S_SM,
                                               float* __restrict__ outS) {
    __shared__ __align__(16) u16 comb[16][264];
    const int bid = blockIdx.x;
    const int row0 = (bid >> 1) * 16;
    const int nbase = (bid & 1) * 128;
    const int t = threadIdx.x;
    {  // phase A: thread = (row, 16-ch group); fills all 256 ch
        int rowi = t >> 4, chg = (t & 15) * 16;
        int grow = row0 + rowi;
        int b = grow >> 10, q = grow & 1023;
        int hh = chg >> 5, d0 = chg & 31;
        const u16* ob = Op + ((size_t)(b * 8 + hh) * 1024 + q) * 32 + d0;
        float a[16];
#pragma unroll
        for (int j = 0; j < 16; ++j) a[j] = 0.f;
        float LS = 0.f;
#pragma unroll
        for (int s = 0; s < 4; ++s) {
            short8 v0 = *(const short8*)(ob + (size_t)s * 16384 * 32);
            short8 v1 = *(const short8*)(ob + (size_t)s * 16384 * 32 + 8);
#pragma unroll
            for (int j = 0; j < 8; ++j) {
                a[j] += b2f((u16)v0[j]);
                a[8 + j] += b2f((u16)v1[j]);
            }
            LS += Lp[(size_t)s * 16384 + (size_t)(b * 8 + hh) * 1024 + q];
        }
        float il = 1.f / LS;
#pragma unroll
        for (int g = 0; g < 4; ++g) {
            ushort4 pk = {bf16r(a[g * 4] * il), bf16r(a[g * 4 + 1] * il),
                          bf16r(a[g * 4 + 2] * il), bf16r(a[g * 4 + 3] * il)};
            *(ushort4*)&comb[rowi][chg + g * 4] = pk;
        }
    }
    __syncthreads();
    const int wv = t >> 6, lane = t & 63;
    const int lm = lane & 15, quad = lane >> 4;
    short8 af[8];
#pragma unroll
    for (int i = 0; i < 8; ++i)
        af[i] = *(const short8*)&comb[lm][i * 32 + quad * 8];
    // paired-j weight prefetch (16 loads in flight)
    short8 wfr2[2][8];
#pragma unroll
    for (int j = 0; j < 2; ++j) {
        int n = nbase + wv * 32 + j * 16 + lm;
        const u16* wp = Wf2T + (size_t)n * 256 + quad * 8;
#pragma unroll
        for (int i = 0; i < 8; ++i) wfr2[j][i] = *(const short8*)(wp + i * 32);
    }
    f32x4 acc[2];
#pragma unroll
    for (int j = 0; j < 2; ++j) {
        int n = nbase + wv * 32 + j * 16 + lm;
        float bvv = bf2[n];
        acc[j] = f32x4{bvv, bvv, bvv, bvv};
#pragma unroll
        for (int i = 0; i < 8; ++i)
            acc[j] = __builtin_amdgcn_mfma_f32_16x16x32_bf16(af[i], wfr2[j][i], acc[j], 0, 0, 0);
    }
#pragma unroll
    for (int j = 0; j < 2; ++j) {
        int n = nbase + wv * 32 + j * 16 + lm;
#pragma unroll
        for (int r = 0; r < 4; ++r) {
            int row = row0 + quad * 4 + r;
            outS[(size_t)row * 256 + n] = S_SM[(size_t)row * 256 + n] - acc[j][r];
        }
    }
}

extern "C" void kernel_launch(void* const* d_in, const int* in_sizes, int n_in,
                              void* d_out, int out_size, void* d_ws, size_t ws_size,
                              hipStream_t stream) {
    const float* S_QP = (const float*)d_in[0];
    const float* S_SM = (const float*)d_in[1];
    const float* f_q = (const float*)d_in[2];
    const float* P = (const float*)d_in[3];
    const float* qp_W1 = (const float*)d_in[4];
    const float* qp_b1 = (const float*)d_in[5];
    const float* qp_W2 = (const float*)d_in[6];
    const float* qp_b2 = (const float*)d_in[7];
    const float* phiQ_W1 = (const float*)d_in[8];
    const float* phiQ_b1 = (const float*)d_in[9];
    const float* phiQ_W2 = (const float*)d_in[10];
    const float* phiQ_b2 = (const float*)d_in[11];
    const float* Wq = (const float*)d_in[12];
    const float* bq = (const float*)d_in[13];
    const float* Wk = (const float*)d_in[14];
    const float* bk = (const float*)d_in[15];
    const float* Wv = (const float*)d_in[16];
    const float* bv = (const float*)d_in[17];
    const float* Wo = (const float*)d_in[18];
    const float* bo = (const float*)d_in[19];
    const float* phi_W = (const float*)d_in[20];
    const float* phi_b = (const float*)d_in[21];

    float* out = (float*)d_out;
    float* outS = out;            // [2,1024,256]
    float* outP = out + 524288;   // [2,2,64,64]
    float* outV = out + 540672;   // [2,1,64,64]

    float* sbp = (float*)d_ws;             // 8192 (32 slabs x 256)
    float* Lp = sbp + 8192;                // 131072 (use 65536: 4sp x 16384)
    float* bf1 = Lp + 131072;              // 256
    float* bf2 = bf1 + 256;                // 256
    u16* qpW1loT = (u16*)(bf2 + 256);      // 65536
    u16* WkT = qpW1loT + 65536;
    u16* WvT = WkT + 65536;
    u16* phiQ1T = WvT + 65536;             // 131072 (256x512)
    u16* Wf1T = phiQ1T + 131072;
    u16* Wf2T = Wf1T + 65536;
    u16* evb = Wf2T + 65536;               // 8192 (bf16, kv-permuted)
    u16* qmb = evb + 8192;                 // 524288
    u16* kmb = qmb + 524288;               // 2097152
    u16* vtb = kmb + 2097152;              // 2097152 (V^T * e, kv-permuted)
    u16* Op16 = vtb + 2097152;             // 4194304 (use 2097152: 4sp)

    const float qscale = 0.17677669529663687f * LOG2E;

    k1_prep<<<386, 256, 0, stream>>>(qp_W1 + 65536, Wk, Wv, phiQ_W1, Wq, phi_W,
                                     phiQ_W2, Wo, qpW1loT, WkT, WvT, phiQ1T,
                                     Wf1T, Wf2T, phiQ_b2, bq, bo, phi_b,
                                     bf1, bf2, S_SM, qp_W1, sbp);
    k3_proj<<<384, 512, 0, stream>>>(f_q, qpW1loT, WkT, WvT, sbp, qp_b1,
                                     qp_W2, qp_b2, P, bk, bv, outP, outV, evb,
                                     kmb, vtb, S_QP, S_SM, phiQ1T, phiQ_b1,
                                     Wf1T, bf1, qscale, qmb);
    attn_mfma<<<512, 256, 0, stream>>>(qmb, kmb, vtb, evb, Op16, Lp);
    k56_out<<<256, 256, 0, stream>>>(Op16, Lp, Wf2T, bf2, S_SM, outS);
}

// Round 10
// 157.820 us; speedup vs baseline: 1.0422x; 1.0422x over previous
//
#include <hip/hip_runtime.h>
#include <math.h>

// B=2, Lq=1024, C=256, H=W=64 -> Lk=4096, NC=2, NH=8, D=32.
// R19: revert to R15 (session-best verified, 159.4 us). R18's paired-jj
// weight prefetch regressed (+4.7 us, VGPR live-range pressure); R17's
// counted-vmcnt was a statistical tie. R15 structure:
//  - attn: K_STEP=128 (half-major LDS, 48KB), sp-split x4, __syncthreads.
//  - k3: BM=32, single ILP region for qp+K+V (wfr[8] per-jj), K stored
//    after compute, V accs held across barriers; coalesced staging.
//  - k1: fused-weight GEMMs + slab-parallel sbias partial matvec.
//  - k56: combine 4 sp partials + final GEMM, col-split x2.

#define LQ 1024
#define HW 4096
#define LOG2E 1.4426950408889634f

typedef __attribute__((ext_vector_type(8))) short short8;
typedef __attribute__((ext_vector_type(4))) float f32x4;
typedef unsigned short u16;

__device__ __forceinline__ u16 bf16r(float x) {
    unsigned int u = __float_as_uint(x);
    u = (u + 0x7FFFu + ((u >> 16) & 1u)) >> 16;
    return (u16)u;
}

__device__ __forceinline__ float b2f(u16 v) {
    return __uint_as_float((unsigned)v << 16);
}

__device__ __forceinline__ float ent2(float a, float b) {
    float m  = fmaxf(a, b);
    float e0 = expf(a - m), e1 = expf(b - m);
    float iz = 1.f / (e0 + e1);
    float p0 = fmaxf(e0 * iz, 1e-8f);
    float p1 = fmaxf(e1 * iz, 1e-8f);
    return -(p0 * logf(p0) + p1 * logf(p1));
}

typedef __attribute__((address_space(1))) const unsigned int gas_u32;
typedef __attribute__((address_space(3))) unsigned int las_u32;
__device__ __forceinline__ void glds16(const void* g, void* l) {
    __builtin_amdgcn_global_load_lds((gas_u32*)g, (las_u32*)l, 16, 0, 0);
}

// kv-permutation within a 32-group: p(16t + 4q2 + r) = 8*q2 + 4*t + r
__device__ __forceinline__ int kvperm(int l) {
    int w = l & 31;
    return (l & ~31) | (((w >> 2) & 3) << 3) | (((w >> 4) & 1) << 2) | (w & 3);
}

// ---- fused-weight GEMM, all-inline from fp32:
// out16[a*256+b] = sum_o G[o*256+a] * S[b*256+o]
__device__ __forceinline__ void fuse_gemm(int bid, const float* __restrict__ G,
                                          const float* __restrict__ S,
                                          u16* __restrict__ out16) {
    const int wv = threadIdx.x >> 6, lane = threadIdx.x & 63;
    const int lm = lane & 15, quad = lane >> 4;
    const int row0 = (bid >> 1) * 32;          // a
    const int c0 = (bid & 1) * 128 + wv * 32;  // b
    short8 af[2][8];
#pragma unroll
    for (int s = 0; s < 2; ++s)
#pragma unroll
        for (int i = 0; i < 8; ++i) {
            short8 t;
#pragma unroll
            for (int j = 0; j < 8; ++j)
                t[j] = (short)bf16r(G[(size_t)(i * 32 + quad * 8 + j) * 256 +
                                      row0 + s * 16 + lm]);
            af[s][i] = t;
        }
#pragma unroll
    for (int j = 0; j < 2; ++j) {
        int b = c0 + j * 16 + lm;
        f32x4 acc[2];
        acc[0] = f32x4{0.f, 0.f, 0.f, 0.f};
        acc[1] = acc[0];
#pragma unroll
        for (int i = 0; i < 8; ++i) {
            const float* sp = S + (size_t)b * 256 + i * 32 + quad * 8;
            float4 f0 = *(const float4*)sp;
            float4 f1 = *(const float4*)(sp + 4);
            short8 bfv;
            bfv[0] = (short)bf16r(f0.x); bfv[1] = (short)bf16r(f0.y);
            bfv[2] = (short)bf16r(f0.z); bfv[3] = (short)bf16r(f0.w);
            bfv[4] = (short)bf16r(f1.x); bfv[5] = (short)bf16r(f1.y);
            bfv[6] = (short)bf16r(f1.z); bfv[7] = (short)bf16r(f1.w);
#pragma unroll
            for (int s = 0; s < 2; ++s)
                acc[s] = __builtin_amdgcn_mfma_f32_16x16x32_bf16(af[s][i], bfv,
                                                                 acc[s], 0, 0, 0);
        }
#pragma unroll
        for (int s = 0; s < 2; ++s)
#pragma unroll
            for (int r = 0; r < 4; ++r)
                out16[(size_t)(row0 + s * 16 + quad * 4 + r) * 256 + b] =
                    bf16r(acc[s][r]);
    }
}

// ======== K1: prep (386 blocks)
__global__ __launch_bounds__(256) void k1_prep(
    const float* qpW1hi, const float* Wk, const float* Wv, const float* phiQ1,
    const float* Wq, const float* phiW, const float* phiQ2, const float* Wo,
    u16* qpW1loT, u16* WkT, u16* WvT, u16* phiQ1T, u16* Wf1T, u16* Wf2T,
    const float* pb2, const float* bq, const float* bo, const float* phib,
    float* bf1, float* bf2,
    const float* S_SM, const float* qpW1full, float* sbp) {
    __shared__ float tile[32][33];
    __shared__ float part_s[256];
    __shared__ float4 red4[4][64];
    int bid = blockIdx.x;
    if (bid < 320) {  // transposes W[K,256] -> Wt[256,K] bf16
        const float* S; u16* D; int K;
        if (bid < 64)       { S = qpW1hi; D = qpW1loT; K = 256; }
        else if (bid < 128) { S = Wk; D = WkT; K = 256; bid -= 64; }
        else if (bid < 192) { S = Wv; D = WvT; K = 256; bid -= 128; }
        else                { S = phiQ1; D = phiQ1T; K = 512; bid -= 192; }
        int KT = K >> 5;
        int tk = bid % KT, tn = bid / KT;
        int cc = threadIdx.x & 31, rb = threadIdx.x >> 5;
#pragma unroll
        for (int i = 0; i < 4; ++i) {
            int rr = rb + i * 8;
            tile[rr][cc] = S[(size_t)(tk * 32 + rr) * 256 + tn * 32 + cc];
        }
        __syncthreads();
#pragma unroll
        for (int i = 0; i < 4; ++i) {
            int rr = rb + i * 8;
            D[(size_t)(tn * 32 + rr) * K + tk * 32 + cc] = bf16r(tile[cc][rr]);
        }
    } else if (bid < 336) {  // Wf1T[n][c] = sum_o phiQ2[c][o] * Wq[o][n]
        fuse_gemm(bid - 320, Wq, phiQ2, Wf1T);
    } else if (bid < 352) {  // Wf2T[n][d] = sum_o Wo[d][o] * phiW[o][n]
        fuse_gemm(bid - 336, phiW, Wo, Wf2T);
    } else if (bid < 354) {  // bias_fuse
        int n = threadIdx.x;
        if (bid == 352) {
            float a = bq[n];
            for (int c = 0; c < 256; ++c) a += pb2[c] * Wq[c * 256 + n];
            bf1[n] = a;
        } else {
            float a = phib[n];
            for (int c = 0; c < 256; ++c) a += bo[c] * phiW[c * 256 + n];
            bf2[n] = a;
        }
    } else {  // mean partial + partial sbias matvec: 32 slabs of 64 rows
        int bi = bid - 354;
        int bb = bi >> 4, l0 = (bi & 15) * 64;
        int c = threadIdx.x;
        const float* p = S_SM + (size_t)bb * LQ * 256 + (size_t)l0 * 256 + c;
        float acc = 0.f;
#pragma unroll 8
        for (int l = 0; l < 64; ++l) acc += p[(size_t)l * 256];
        part_s[c] = acc;
        __syncthreads();
        const int g = threadIdx.x & 63, qtr = threadIdx.x >> 6;
        float a0 = 0.f, a1 = 0.f, a2 = 0.f, a3 = 0.f;
        const float* wbase = qpW1full + (size_t)(qtr * 64) * 256 + g * 4;
#pragma unroll 8
        for (int i = 0; i < 64; ++i) {
            float pp = part_s[qtr * 64 + i];
            float4 w = *(const float4*)(wbase + (size_t)i * 256);
            a0 += pp * w.x; a1 += pp * w.y; a2 += pp * w.z; a3 += pp * w.w;
        }
        red4[qtr][g] = float4{a0, a1, a2, a3};
        __syncthreads();
        if (threadIdx.x < 64) {
            int t = threadIdx.x;
            float4 r0 = red4[0][t], r1 = red4[1][t], r2 = red4[2][t], r3 = red4[3][t];
            float4 s;
            s.x = r0.x + r1.x + r2.x + r3.x;
            s.y = r0.y + r1.y + r2.y + r3.y;
            s.z = r0.z + r1.z + r2.z + r3.z;
            s.w = r0.w + r1.w + r2.w + r3.w;
            *(float4*)(sbp + (size_t)bi * 256 + t * 4) = s;
        }
    }
}

// ======== K3: proj (384 blocks x 512 threads)
// [0,256): fused qp+K+V, BM=32, single ILP region for all 3 GEMMs
// [256,384): phiQ1 + q-projection fused, BM=16
__global__ __launch_bounds__(512, 2) void k3_proj(
    const float* __restrict__ f_q, const u16* __restrict__ Wqp,
    const u16* __restrict__ Wk, const u16* __restrict__ Wv,
    const float* __restrict__ sbp, const float* __restrict__ qpb1,
    const float* __restrict__ qpW2, const float* __restrict__ qpb2,
    const float* __restrict__ P, const float* __restrict__ bk,
    const float* __restrict__ bv,
    float* __restrict__ outPhat, float* __restrict__ outV,
    u16* __restrict__ evb, u16* __restrict__ kmb, u16* __restrict__ vtb,
    const float* __restrict__ S_QP, const float* __restrict__ S_SM,
    const u16* __restrict__ phiQ1T, const float* __restrict__ phiQb1,
    const u16* __restrict__ Wf1T, const float* __restrict__ bf1,
    float qscale, u16* __restrict__ qmb) {
    __shared__ __align__(16) u16 shmem[32 * 264];
    __shared__ float sb_s[256];
    __shared__ float red[8][32][2];
    __shared__ float evl[32];
    const int bid = blockIdx.x;
    const int tid = threadIdx.x;
    const int wv = tid >> 6, lane = tid & 63;
    const int lm = lane & 15, quad = lane >> 4;
    if (bid >= 256) {  // ---- phiQ1 + q-proj fused: 16 rows per block
        __shared__ __align__(16) u16 fs2[16 * 520];
        u16* qs = shmem;  // [16][264] Qmid
        const int row0 = (bid - 256) * 16;
        {   // stage (coalesced): 16-lane halves read 1KB contiguous rows
            int r = tid >> 5, cg = tid & 31;
            const float* src = (cg < 16)
                ? (S_QP + (size_t)(row0 + r) * 256 + cg * 16)
                : (S_SM + (size_t)(row0 + r) * 256 + (cg - 16) * 16);
            u16* dst = fs2 + r * 520 + cg * 16;
#pragma unroll
            for (int q4 = 0; q4 < 4; ++q4) {
                float4 f0 = *(const float4*)(src + q4 * 4);
                dst[q4 * 4 + 0] = bf16r(f0.x);
                dst[q4 * 4 + 1] = bf16r(f0.y);
                dst[q4 * 4 + 2] = bf16r(f0.z);
                dst[q4 * 4 + 3] = bf16r(f0.w);
            }
        }
        __syncthreads();
        short8 af[16];
#pragma unroll
        for (int i = 0; i < 16; ++i)
            af[i] = *(const short8*)(fs2 + lm * 520 + i * 32 + quad * 8);
#pragma unroll
        for (int j = 0; j < 2; ++j) {
            int n = wv * 32 + j * 16 + lm;
            short8 wfr[16];
            const u16* wp = phiQ1T + (size_t)n * 512 + quad * 8;
#pragma unroll
            for (int i = 0; i < 16; ++i) wfr[i] = *(const short8*)(wp + i * 32);
            float bvv = phiQb1[n];
            f32x4 acc = {bvv, bvv, bvv, bvv};
#pragma unroll
            for (int i = 0; i < 16; ++i)
                acc = __builtin_amdgcn_mfma_f32_16x16x32_bf16(af[i], wfr[i], acc, 0, 0, 0);
#pragma unroll
            for (int r = 0; r < 4; ++r)
                qs[(quad * 4 + r) * 264 + n] = bf16r(fmaxf(acc[r], 0.f));
        }
        __syncthreads();
        short8 aq[8];
#pragma unroll
        for (int i = 0; i < 8; ++i)
            aq[i] = *(const short8*)(qs + lm * 264 + i * 32 + quad * 8);
#pragma unroll
        for (int j = 0; j < 2; ++j) {
            int n = wv * 32 + j * 16 + lm;
            short8 wfr[8];
            const u16* wp = Wf1T + (size_t)n * 256 + quad * 8;
#pragma unroll
            for (int i = 0; i < 8; ++i) wfr[i] = *(const short8*)(wp + i * 32);
            float bvv = bf1[n];
            f32x4 acc = {bvv, bvv, bvv, bvv};
#pragma unroll
            for (int i = 0; i < 8; ++i)
                acc = __builtin_amdgcn_mfma_f32_16x16x32_bf16(aq[i], wfr[i], acc, 0, 0, 0);
#pragma unroll
            for (int r = 0; r < 4; ++r)
                qmb[(size_t)(row0 + quad * 4 + r) * 256 + n] = bf16r(acc[r] * qscale);
        }
        return;
    }
    // ---- fused qp + K + V, BM=32
    u16* fs = shmem;  // [32][264] staged f_q tile (bf16), [pos][ch]
    const int row0 = bid * 32;
    const int b = row0 >> 12;
    const int l = row0 & 4095;
    {   // stage (coalesced): 8-lane groups read 128B contiguous per ch row
        int cg = tid >> 3;        // 0..63
        int l4 = (tid & 7) * 4;   // 0,4,...,28
        const float* fb0 = f_q + (size_t)b * 256 * HW + l;
#pragma unroll
        for (int g = 0; g < 4; ++g) {
            int c = g * 64 + cg;
            float4 v = *(const float4*)(fb0 + (size_t)c * HW + l4);
            u16* dst = fs + c;
            dst[(l4 + 0) * 264] = bf16r(v.x);
            dst[(l4 + 1) * 264] = bf16r(v.y);
            dst[(l4 + 2) * 264] = bf16r(v.z);
            dst[(l4 + 3) * 264] = bf16r(v.w);
        }
    }
    if (tid < 256) {  // sbias: sum 16 precomputed partial matvecs
        float a = 0.f;
#pragma unroll
        for (int p = 0; p < 16; ++p) a += sbp[(b * 16 + p) * 256 + tid];
        sb_s[tid] = qpb1[tid] + a * (1.f / 1024.f);
    }
    __syncthreads();
    short8 af[2][8];  // register-resident A frags
#pragma unroll
    for (int rg = 0; rg < 2; ++rg)
#pragma unroll
        for (int i = 0; i < 8; ++i)
            af[rg][i] = *(const short8*)(fs + (rg * 16 + lm) * 264 + i * 32 + quad * 8);
    // --- single ILP region: qp, K, V accumulators (no barriers inside)
    float c0p[2][4] = {{0.f, 0.f, 0.f, 0.f}, {0.f, 0.f, 0.f, 0.f}};
    float c1p[2][4] = {{0.f, 0.f, 0.f, 0.f}, {0.f, 0.f, 0.f, 0.f}};
    f32x4 kacc[2][2], vacc[2][2];
#pragma unroll
    for (int jj = 0; jj < 2; ++jj) {
        const int n = (wv * 2 + jj) * 16 + lm;
        short8 wfr[8];
        const u16* wp = Wqp + (size_t)n * 256 + quad * 8;
#pragma unroll
        for (int i = 0; i < 8; ++i) wfr[i] = *(const short8*)(wp + i * 32);
        float bv2 = sb_s[n];
        float w20 = qpW2[n * 2], w21 = qpW2[n * 2 + 1];
#pragma unroll
        for (int rg = 0; rg < 2; ++rg) {
            f32x4 acc = {bv2, bv2, bv2, bv2};
#pragma unroll
            for (int i = 0; i < 8; ++i)
                acc = __builtin_amdgcn_mfma_f32_16x16x32_bf16(af[rg][i], wfr[i], acc, 0, 0, 0);
#pragma unroll
            for (int r = 0; r < 4; ++r) {
                float hh2 = fmaxf(acc[r], 0.f);
                c0p[rg][r] += hh2 * w20;
                c1p[rg][r] += hh2 * w21;
            }
        }
    }
#pragma unroll
    for (int jj = 0; jj < 2; ++jj) {
        const int n = (wv * 2 + jj) * 16 + lm;
        short8 wfr[8];
        const u16* wp = Wk + (size_t)n * 256 + quad * 8;
#pragma unroll
        for (int i = 0; i < 8; ++i) wfr[i] = *(const short8*)(wp + i * 32);
        float bk2 = bk[n];
#pragma unroll
        for (int rg = 0; rg < 2; ++rg) {
            f32x4 acc = {bk2, bk2, bk2, bk2};
#pragma unroll
            for (int i = 0; i < 8; ++i)
                acc = __builtin_amdgcn_mfma_f32_16x16x32_bf16(af[rg][i], wfr[i], acc, 0, 0, 0);
            kacc[jj][rg] = acc;
        }
    }
#pragma unroll
    for (int jj = 0; jj < 2; ++jj) {
        const int n = (wv * 2 + jj) * 16 + lm;
        short8 wfr[8];
        const u16* wp = Wv + (size_t)n * 256 + quad * 8;
#pragma unroll
        for (int i = 0; i < 8; ++i) wfr[i] = *(const short8*)(wp + i * 32);
        float bv2 = bv[n];
#pragma unroll
        for (int rg = 0; rg < 2; ++rg) {
            f32x4 acc = {bv2, bv2, bv2, bv2};
#pragma unroll
            for (int i = 0; i < 8; ++i)
                acc = __builtin_amdgcn_mfma_f32_16x16x32_bf16(af[rg][i], wfr[i], acc, 0, 0, 0);
            vacc[jj][rg] = acc;
        }
    }
    // K store (no cross-thread dependency)
#pragma unroll
    for (int jj = 0; jj < 2; ++jj) {
        const int n = (wv * 2 + jj) * 16 + lm;
#pragma unroll
        for (int rg = 0; rg < 2; ++rg)
#pragma unroll
            for (int r = 0; r < 4; ++r)
                kmb[(size_t)(row0 + rg * 16 + quad * 4 + r) * 256 + n] =
                    bf16r(kacc[jj][rg][r]);
    }
    // qp wave reduce
#pragma unroll
    for (int m = 1; m < 16; m <<= 1) {
#pragma unroll
        for (int rg = 0; rg < 2; ++rg)
#pragma unroll
            for (int r = 0; r < 4; ++r) {
                c0p[rg][r] += __shfl_xor(c0p[rg][r], m);
                c1p[rg][r] += __shfl_xor(c1p[rg][r], m);
            }
    }
    if (lm == 0) {
#pragma unroll
        for (int rg = 0; rg < 2; ++rg)
#pragma unroll
            for (int r = 0; r < 4; ++r) {
                red[wv][rg * 16 + quad * 4 + r][0] = c0p[rg][r];
                red[wv][rg * 16 + quad * 4 + r][1] = c1p[rg][r];
            }
    }
    __syncthreads();
    if (tid < 32) {
        int t = tid;
        float ph0 = qpb2[0], ph1 = qpb2[1];
#pragma unroll
        for (int w = 0; w < 8; ++w) {
            ph0 += red[w][t][0];
            ph1 += red[w][t][1];
        }
        int hw = l + t;
        float Vv = ent2(ph0, ph1) -
                   ent2(P[(size_t)b * 8192 + hw], P[(size_t)b * 8192 + 4096 + hw]);
        outPhat[(size_t)b * 8192 + hw] = ph0;
        outPhat[(size_t)b * 8192 + 4096 + hw] = ph1;
        outV[b * 4096 + hw] = Vv;
        float ev = expf(Vv);
        evl[t] = ev;
        evb[b * HW + kvperm(hw)] = bf16r(ev);
    }
    __syncthreads();  // evl visible to all
    // V scale + store (kvperm, r-packed)
#pragma unroll
    for (int jj = 0; jj < 2; ++jj) {
        const int n = (wv * 2 + jj) * 16 + lm;
#pragma unroll
        for (int rg = 0; rg < 2; ++rg) {
            const int pbase = l | (quad << 3) | (rg << 2);
            ushort4 pk;
            pk.x = bf16r(vacc[jj][rg][0] * evl[rg * 16 + quad * 4 + 0]);
            pk.y = bf16r(vacc[jj][rg][1] * evl[rg * 16 + quad * 4 + 1]);
            pk.z = bf16r(vacc[jj][rg][2] * evl[rg * 16 + quad * 4 + 2]);
            pk.w = bf16r(vacc[jj][rg][3] * evl[rg * 16 + quad * 4 + 3]);
            *(ushort4*)(vtb + ((size_t)((b * 8 + (n >> 5)) * 32 + (n & 31))) * HW +
                        pbase) = pk;
        }
    }
}

// ======== K4: MFMA flash attention (R9 form, sp-split x4, K_STEP=128)
__global__ __launch_bounds__(256) void attn_mfma(const u16* __restrict__ qm,
                                                 const u16* __restrict__ km,
                                                 const u16* __restrict__ vt,
                                                 const u16* __restrict__ evb,
                                                 u16* __restrict__ Op,
                                                 float* __restrict__ Lp) {
    // half-major: Kst[buf][half][kv 64][d 32], Vst[buf][half][d 32][kv' 64]
    __shared__ __align__(16) u16 Kst[3][4096];
    __shared__ __align__(16) u16 Vst[3][4096];
    const int blk = blockIdx.x;   // 512 = 2b * 8qt * 4sp * 8h
    const int h = blk & 7, sp = (blk >> 3) & 3, qt = (blk >> 5) & 7, b = blk >> 8;
    const int tid = threadIdx.x;
    const int wv = tid >> 6, lane = tid & 63;
    const int lm = lane & 15, quad = lane >> 4;
    const int q0 = qt * 128 + wv * 32;
    short8 qf[2];
#pragma unroll
    for (int s = 0; s < 2; ++s)
        qf[s] = *(const short8*)(qm + ((size_t)(b * LQ + q0 + s * 16 + lm)) * 256 +
                                 h * 32 + quad * 8);
    const u16* kbh = km + (size_t)b * HW * 256 + h * 32;
    const u16* vbh = vt + (size_t)(b * 8 + h) * 32 * HW;
    const u16* eb = evb + (size_t)b * HW;
    const int krow = tid >> 2, kseg = tid & 3;
    const int vd = tid >> 3, vp = tid & 7, vs = (vp - vd) & 7;
    const int kv_lo = sp * 1024;
    const f32x4 z4 = {0.f, 0.f, 0.f, 0.f};
    f32x4 o[2][2] = {{z4, z4}, {z4, z4}};  // [qfrag][dtile], O^T C-layout
    f32x4 lr[2] = {z4, z4};
    const int vss = (quad + lm) & 7;
#define LOADT(ib, kvoff)                                                          \
    {                                                                             \
        glds16(kbh + (size_t)((kvoff) + krow) * 256 + kseg * 8,                   \
               &Kst[ib][wv * 512]);                                               \
        glds16(kbh + (size_t)((kvoff) + 64 + krow) * 256 + kseg * 8,              \
               &Kst[ib][2048 + wv * 512]);                                        \
        glds16(vbh + (size_t)vd * HW + (kvoff) + vs * 8, &Vst[ib][wv * 512]);     \
        glds16(vbh + (size_t)vd * HW + (kvoff) + 64 + vs * 8,                     \
               &Vst[ib][2048 + wv * 512]);                                        \
    }
    LOADT(0, kv_lo);
    LOADT(1, kv_lo + 128);
    for (int c = 0; c < 8; ++c) {
        __syncthreads();
        if (c + 2 < 8) LOADT((c + 2) % 3, kv_lo + (c + 2) * 128);
        const int idx = c % 3;
#pragma unroll
        for (int half = 0; half < 2; ++half) {
            const int kc = kv_lo + c * 128 + half * 64;
            const u16* kbuf = &Kst[idx][half * 2048];
            const u16* vbuf = &Vst[idx][half * 2048];
            f32x4 st[2][4];
#pragma unroll
            for (int tt = 0; tt < 4; ++tt) {
                short8 kf = *(const short8*)(kbuf + (tt * 16 + lm) * 32 + quad * 8);
                st[0][tt] = __builtin_amdgcn_mfma_f32_16x16x32_bf16(kf, qf[0], z4, 0, 0, 0);
                st[1][tt] = __builtin_amdgcn_mfma_f32_16x16x32_bf16(kf, qf[1], z4, 0, 0, 0);
            }
            short8 pf[2][2];
#pragma unroll
            for (int s = 0; s < 2; ++s)
#pragma unroll
                for (int c2 = 0; c2 < 2; ++c2) {
                    short8 pk;
#pragma unroll
                    for (int j = 0; j < 8; ++j) {
                        float pv = __builtin_amdgcn_exp2f(st[s][c2 * 2 + (j >> 2)][j & 3]);
                        pk[j] = (short)(__float_as_uint(pv) >> 16);
                    }
                    pf[s][c2] = pk;
                }
#pragma unroll
            for (int c2 = 0; c2 < 2; ++c2) {
                short8 ef = *(const short8*)(eb + kc + c2 * 32 + quad * 8);
                short8 vf0 = *(const short8*)(vbuf + lm * 64 + ((c2 * 4 + vss) & 7) * 8);
                short8 vf1 = *(const short8*)(vbuf + (16 + lm) * 64 + ((c2 * 4 + vss) & 7) * 8);
#pragma unroll
                for (int s = 0; s < 2; ++s) {
                    lr[s] = __builtin_amdgcn_mfma_f32_16x16x32_bf16(ef, pf[s][c2], lr[s], 0, 0, 0);
                    o[s][0] = __builtin_amdgcn_mfma_f32_16x16x32_bf16(vf0, pf[s][c2], o[s][0], 0, 0, 0);
                    o[s][1] = __builtin_amdgcn_mfma_f32_16x16x32_bf16(vf1, pf[s][c2], o[s][1], 0, 0, 0);
                }
            }
        }
    }
#undef LOADT
#pragma unroll
    for (int s = 0; s < 2; ++s) {
        int qg = q0 + s * 16 + lm;
        size_t rbase = (size_t)sp * 16384 + (size_t)(b * 8 + h) * LQ + qg;
#pragma unroll
        for (int dt = 0; dt < 2; ++dt)
#pragma unroll
            for (int r = 0; r < 4; ++r)
                Op[rbase * 32 + dt * 16 + quad * 4 + r] = bf16r(o[s][dt][r]);
        if (quad == 0) Lp[rbase] = lr[s][0];
    }
}

// ======== K56: combine (4 sp partials) + final GEMM, col-split x2 (256 blocks).
__global__ __launch_bounds__(256) void k56_out(const u16* __restrict__ Op,
                                               const float* __restrict__ Lp,
                                               const u16* __restrict__ Wf2T,
                                               const float* __restrict__ bf2,
                                               const float* __restrict__ S_SM,
                                               float* __restrict__ outS) {
    __shared__ __align__(16) u16 comb[16][264];
    const int bid = blockIdx.x;
    const int row0 = (bid >> 1) * 16;
    const int nbase = (bid & 1) * 128;
    const int t = threadIdx.x;
    {  // phase A: thread = (row, 16-ch group); fills all 256 ch
        int rowi = t >> 4, chg = (t & 15) * 16;
        int grow = row0 + rowi;
        int b = grow >> 10, q = grow & 1023;
        int hh = chg >> 5, d0 = chg & 31;
        const u16* ob = Op + ((size_t)(b * 8 + hh) * 1024 + q) * 32 + d0;
        float a[16];
#pragma unroll
        for (int j = 0; j < 16; ++j) a[j] = 0.f;
        float LS = 0.f;
#pragma unroll
        for (int s = 0; s < 4; ++s) {
            short8 v0 = *(const short8*)(ob + (size_t)s * 16384 * 32);
            short8 v1 = *(const short8*)(ob + (size_t)s * 16384 * 32 + 8);
#pragma unroll
            for (int j = 0; j < 8; ++j) {
                a[j] += b2f((u16)v0[j]);
                a[8 + j] += b2f((u16)v1[j]);
            }
            LS += Lp[(size_t)s * 16384 + (size_t)(b * 8 + hh) * 1024 + q];
        }
        float il = 1.f / LS;
#pragma unroll
        for (int g = 0; g < 4; ++g) {
            ushort4 pk = {bf16r(a[g * 4] * il), bf16r(a[g * 4 + 1] * il),
                          bf16r(a[g * 4 + 2] * il), bf16r(a[g * 4 + 3] * il)};
            *(ushort4*)&comb[rowi][chg + g * 4] = pk;
        }
    }
    __syncthreads();
    const int wv = t >> 6, lane = t & 63;
    const int lm = lane & 15, quad = lane >> 4;
    short8 af[8];
#pragma unroll
    for (int i = 0; i < 8; ++i)
        af[i] = *(const short8*)&comb[lm][i * 32 + quad * 8];
    f32x4 acc[2];
#pragma unroll
    for (int j = 0; j < 2; ++j) {
        int n = nbase + wv * 32 + j * 16 + lm;
        float bvv = bf2[n];
        acc[j] = f32x4{bvv, bvv, bvv, bvv};
        const u16* wp = Wf2T + (size_t)n * 256 + quad * 8;
#pragma unroll
        for (int i = 0; i < 8; ++i) {
            short8 bfv = *(const short8*)(wp + i * 32);
            acc[j] = __builtin_amdgcn_mfma_f32_16x16x32_bf16(af[i], bfv, acc[j], 0, 0, 0);
        }
    }
#pragma unroll
    for (int j = 0; j < 2; ++j) {
        int n = nbase + wv * 32 + j * 16 + lm;
#pragma unroll
        for (int r = 0; r < 4; ++r) {
            int row = row0 + quad * 4 + r;
            outS[(size_t)row * 256 + n] = S_SM[(size_t)row * 256 + n] - acc[j][r];
        }
    }
}

extern "C" void kernel_launch(void* const* d_in, const int* in_sizes, int n_in,
                              void* d_out, int out_size, void* d_ws, size_t ws_size,
                              hipStream_t stream) {
    const float* S_QP = (const float*)d_in[0];
    const float* S_SM = (const float*)d_in[1];
    const float* f_q = (const float*)d_in[2];
    const float* P = (const float*)d_in[3];
    const float* qp_W1 = (const float*)d_in[4];
    const float* qp_b1 = (const float*)d_in[5];
    const float* qp_W2 = (const float*)d_in[6];
    const float* qp_b2 = (const float*)d_in[7];
    const float* phiQ_W1 = (const float*)d_in[8];
    const float* phiQ_b1 = (const float*)d_in[9];
    const float* phiQ_W2 = (const float*)d_in[10];
    const float* phiQ_b2 = (const float*)d_in[11];
    const float* Wq = (const float*)d_in[12];
    const float* bq = (const float*)d_in[13];
    const float* Wk = (const float*)d_in[14];
    const float* bk = (const float*)d_in[15];
    const float* Wv = (const float*)d_in[16];
    const float* bv = (const float*)d_in[17];
    const float* Wo = (const float*)d_in[18];
    const float* bo = (const float*)d_in[19];
    const float* phi_W = (const float*)d_in[20];
    const float* phi_b = (const float*)d_in[21];

    float* out = (float*)d_out;
    float* outS = out;            // [2,1024,256]
    float* outP = out + 524288;   // [2,2,64,64]
    float* outV = out + 540672;   // [2,1,64,64]

    float* sbp = (float*)d_ws;             // 8192 (32 slabs x 256)
    float* Lp = sbp + 8192;                // 131072 (use 65536: 4sp x 16384)
    float* bf1 = Lp + 131072;              // 256
    float* bf2 = bf1 + 256;                // 256
    u16* qpW1loT = (u16*)(bf2 + 256);      // 65536
    u16* WkT = qpW1loT + 65536;
    u16* WvT = WkT + 65536;
    u16* phiQ1T = WvT + 65536;             // 131072 (256x512)
    u16* Wf1T = phiQ1T + 131072;
    u16* Wf2T = Wf1T + 65536;
    u16* evb = Wf2T + 65536;               // 8192 (bf16, kv-permuted)
    u16* qmb = evb + 8192;                 // 524288
    u16* kmb = qmb + 524288;               // 2097152
    u16* vtb = kmb + 2097152;              // 2097152 (V^T * e, kv-permuted)
    u16* Op16 = vtb + 2097152;             // 4194304 (use 2097152: 4sp)

    const float qscale = 0.17677669529663687f * LOG2E;

    k1_prep<<<386, 256, 0, stream>>>(qp_W1 + 65536, Wk, Wv, phiQ_W1, Wq, phi_W,
                                     phiQ_W2, Wo, qpW1loT, WkT, WvT, phiQ1T,
                                     Wf1T, Wf2T, phiQ_b2, bq, bo, phi_b,
                                     bf1, bf2, S_SM, qp_W1, sbp);
    k3_proj<<<384, 512, 0, stream>>>(f_q, qpW1loT, WkT, WvT, sbp, qp_b1,
                                     qp_W2, qp_b2, P, bk, bv, outP, outV, evb,
                                     kmb, vtb, S_QP, S_SM, phiQ1T, phiQ_b1,
                                     Wf1T, bf1, qscale, qmb);
    attn_mfma<<<512, 256, 0, stream>>>(qmb, kmb, vtb, evb, Op16, Lp);
    k56_out<<<256, 256, 0, stream>>>(Op16, Lp, Wf2T, bf2, S_SM, outS);
}